// Round 7
// baseline (1631.906 us; speedup 1.0000x reference)
//
#include <hip/hip_runtime.h>
#include <math.h>

#define B_    4
#define N_    4096
#define DIM_  512
#define H_    8
#define DH_   64
#define M_    256
#define LGRP  16
#define BH_   (B_*H_)
#define SCALE_ 0.125f
#define LN_EPS_ 1e-5f

#define SZ_QKVH (B_*H_*N_*DH_)   /* 8388608 */
#define SZ_LM   (BH_*M_*DH_)     /* 524288  */
#define SZ_MM   (BH_*M_*M_)      /* 2097152 */

typedef unsigned short ushort_t;
typedef __attribute__((ext_vector_type(8))) short bfrag8;
typedef __attribute__((ext_vector_type(4))) float fvec4;

__device__ __forceinline__ ushort_t f2b(float f) {
    unsigned u = __float_as_uint(f);
    unsigned r = (u + 0x7fffu + ((u >> 16) & 1u)) >> 16;
    return (ushort_t)r;
}
__device__ __forceinline__ float b2f(ushort_t s) {
    return __uint_as_float(((unsigned)s) << 16);
}

// ---------------- LayerNorm -> bf16 nx ----------------
__global__ __launch_bounds__(256) void ln_kernel(const float* __restrict__ x,
                                                 const float* __restrict__ w,
                                                 const float* __restrict__ bb,
                                                 ushort_t* __restrict__ nxb) {
    int row = blockIdx.x;
    int t = threadIdx.x;
    const float* xr = x + (size_t)row * DIM_;
    float v0 = xr[t], v1 = xr[t + 256];
    float s = v0 + v1, sq = v0 * v0 + v1 * v1;
    __shared__ float ls[4], lq[4];
    for (int off = 32; off > 0; off >>= 1) {
        s  += __shfl_down(s, off);
        sq += __shfl_down(sq, off);
    }
    int wid = t >> 6, lid = t & 63;
    if (lid == 0) { ls[wid] = s; lq[wid] = sq; }
    __syncthreads();
    if (t == 0) {
        float S = 0, Q = 0;
        for (int i = 0; i < 4; i++) { S += ls[i]; Q += lq[i]; }
        ls[0] = S; lq[0] = Q;
    }
    __syncthreads();
    float mean = ls[0] * (1.f / DIM_);
    float var  = lq[0] * (1.f / DIM_) - mean * mean;
    float rs = rsqrtf(var + LN_EPS_);
    ushort_t* o = nxb + (size_t)row * DIM_;
    o[t]       = f2b((v0 - mean) * rs * w[t]       + bb[t]);
    o[t + 256] = f2b((v1 - mean) * rs * w[t + 256] + bb[t + 256]);
}

// ---------------- transpose + cast fp32 [R][C] -> bf16 [C][R] ----------------
__global__ __launch_bounds__(256) void tcast(const float* __restrict__ in,
                                             ushort_t* __restrict__ outT,
                                             int R, int C) {
    __shared__ float tile[32][33];
    int c0 = blockIdx.x * 32, r0 = blockIdx.y * 32;
    int t = threadIdx.x;
    #pragma unroll
    for (int u = 0; u < 4; u++) {
        int lin = t + 256 * u;
        int r = lin >> 5, c = lin & 31;
        tile[r][c] = in[(size_t)(r0 + r) * C + c0 + c];
    }
    __syncthreads();
    #pragma unroll
    for (int u = 0; u < 4; u++) {
        int lin = t + 256 * u;
        int cc = lin >> 5, rr = lin & 31;
        outT[(size_t)(c0 + cc) * R + r0 + rr] = f2b(tile[rr][cc]);
    }
}

// ---------------- big MFMA GEMM: C[M][N] = A[M][512] @ BT[N][512]^T ----------------
// EPI 0: qkv epilogue (bf16 q/k/v, LDS-coalesced). EPI 1: out = omega*x + bo + C.
template<int EPI>
__global__ __launch_bounds__(256) void gemm_bt128(const ushort_t* __restrict__ A,
                                                  const ushort_t* __restrict__ BT,
                                                  ushort_t* __restrict__ qb,
                                                  ushort_t* __restrict__ kb,
                                                  ushort_t* __restrict__ vb,
                                                  const float* __restrict__ x,
                                                  const float* __restrict__ bo,
                                                  const float* __restrict__ omega,
                                                  float* __restrict__ out) {
    const int K = 512;
    __shared__ __align__(16) ushort_t smem[2 * 128 * 72];
    ushort_t (*As)[72] = (ushort_t(*)[72])smem;
    ushort_t (*Bs)[72] = (ushort_t(*)[72])(smem + 128 * 72);
    int t = threadIdx.x;
    int n0 = blockIdx.x * 128, m0 = blockIdx.y * 128;
    int w = t >> 6, lane = t & 63;
    int wr = (w >> 1) * 64, wc = (w & 1) * 64;
    int l15 = lane & 15, quad = lane >> 4, kq = quad * 8;
    fvec4 acc[4][4] = {};
    int rbase = t >> 3, c8 = (t & 7) * 8;

    for (int kc = 0; kc < K; kc += 64) {
        #pragma unroll
        for (int u = 0; u < 4; u++) {
            int rr = rbase + 32 * u;
            const ushort_t* ga;
            if (EPI == 0) {
                ga = A + (size_t)(m0 + rr) * K + kc + c8;
            } else {
                int grow = m0 + rr; int b_ = grow >> 12, nn = grow & 4095;
                int col = kc + c8; int hd = col >> 6, dd = col & 63;
                ga = A + (((size_t)(b_ * H_ + hd) * N_ + nn) << 6) + dd;
            }
            *(float4*)&As[rr][c8] = *(const float4*)ga;
            *(float4*)&Bs[rr][c8] = *(const float4*)(BT + (size_t)(n0 + rr) * K + kc + c8);
        }
        __syncthreads();
        #pragma unroll
        for (int ks = 0; ks < 64; ks += 32) {
            bfrag8 a[4], b[4];
            #pragma unroll
            for (int r = 0; r < 4; r++) a[r] = *(bfrag8*)&As[wr + r * 16 + l15][ks + kq];
            #pragma unroll
            for (int c = 0; c < 4; c++) b[c] = *(bfrag8*)&Bs[wc + c * 16 + l15][ks + kq];
            #pragma unroll
            for (int r = 0; r < 4; r++)
                #pragma unroll
                for (int c = 0; c < 4; c++)
                    acc[r][c] = __builtin_amdgcn_mfma_f32_16x16x32_bf16(a[r], b[c], acc[r][c], 0, 0, 0);
        }
        __syncthreads();
    }

    if (EPI == 0) {
        int sec = n0 >> 9;                     // 0=q 1=k 2=v (tile never crosses)
        float mul = (sec == 0) ? SCALE_ : 1.0f;
        ushort_t (*Ct)[132] = (ushort_t(*)[132])smem;   // 128*132*2 = 33792 <= 36864
        #pragma unroll
        for (int r = 0; r < 4; r++) {
            #pragma unroll
            for (int reg = 0; reg < 4; reg++) {
                int lr = wr + r * 16 + quad * 4 + reg;
                #pragma unroll
                for (int c = 0; c < 4; c++) {
                    int lc = wc + c * 16 + l15;
                    Ct[lr][lc] = f2b(acc[r][c][reg] * mul);
                }
            }
        }
        __syncthreads();
        int row = t & 127, half = t >> 7;
        int grow = m0 + row; int b_ = grow >> 12, nn = grow & 4095;
        int head = ((n0 & 511) >> 6) + half;
        ushort_t* dstbuf = (sec == 0) ? qb : ((sec == 1) ? kb : vb);
        ushort_t* dp = dstbuf + (((size_t)(b_ * H_ + head) * N_ + nn) << 6);
        #pragma unroll
        for (int i = 0; i < 8; i++)
            *(uint4*)(dp + i * 8) = *(uint4*)&Ct[row][half * 64 + i * 8];
    } else {
        float om = omega[0];
        #pragma unroll
        for (int r = 0; r < 4; r++) {
            #pragma unroll
            for (int reg = 0; reg < 4; reg++) {
                int grow = m0 + wr + r * 16 + quad * 4 + reg;
                #pragma unroll
                for (int c = 0; c < 4; c++) {
                    int gcol = n0 + wc + c * 16 + l15;
                    size_t o = (size_t)grow * DIM_ + gcol;
                    out[o] = om * x[o] + bo[gcol] + acc[r][c][reg];
                }
            }
        }
    }
}

// ---------------- landmark means (bf16 in/out, uint4 vectorized) ----------------
__global__ __launch_bounds__(256) void landmark_kernel(const ushort_t* __restrict__ q,
                                                       const ushort_t* __restrict__ k,
                                                       ushort_t* __restrict__ ql,
                                                       ushort_t* __restrict__ kl) {
    int idx = blockIdx.x * 256 + threadIdx.x;    // over SZ_LM/8 = 65536
    const ushort_t* src = blockIdx.y ? k : q;
    ushort_t* dst = blockIdx.y ? kl : ql;
    int d8 = (idx & 7) * 8;
    int m = (idx >> 3) & 255;
    int bh = idx >> 11;
    const ushort_t* p = src + (((size_t)bh * N_) + m * LGRP) * DH_ + d8;
    float s[8] = {};
    #pragma unroll
    for (int j = 0; j < LGRP; j++) {
        union { uint4 u4; ushort_t sv[8]; } val;
        val.u4 = *(const uint4*)(p + (size_t)j * DH_);
        #pragma unroll
        for (int e = 0; e < 8; e++) s[e] += b2f(val.sv[e]);
    }
    union { uint4 u4; ushort_t sv[8]; } o;
    #pragma unroll
    for (int e = 0; e < 8; e++) o.sv[e] = f2b(s[e] * (1.f / LGRP));
    *(uint4*)(dst + ((size_t)bh * M_ + m) * DH_ + d8) = o.u4;
}

// ---------------- sim2 + softmax -> a2 (fp32 + bf16) ----------------
__global__ __launch_bounds__(256) void sim2_softmax(const ushort_t* __restrict__ ql,
                                                    const ushort_t* __restrict__ kl,
                                                    float* __restrict__ a2,
                                                    ushort_t* __restrict__ a2b) {
    int i = blockIdx.x, bh = blockIdx.y, j = threadIdx.x;
    __shared__ float qrow[64];
    __shared__ float red[256];
    if (j < 64) qrow[j] = b2f(ql[((size_t)bh * M_ + i) * DH_ + j]);
    __syncthreads();
    const ushort_t* kr = kl + ((size_t)bh * M_ + j) * DH_;
    float s = 0;
    #pragma unroll
    for (int d = 0; d < 64; d++) s += qrow[d] * b2f(kr[d]);
    red[j] = s; __syncthreads();
    for (int off = 128; off > 0; off >>= 1) {
        if (j < off) red[j] = fmaxf(red[j], red[j + off]);
        __syncthreads();
    }
    float mx = red[0]; __syncthreads();
    float p = __expf(s - mx);
    red[j] = p; __syncthreads();
    for (int off = 128; off > 0; off >>= 1) {
        if (j < off) red[j] += red[j + off];
        __syncthreads();
    }
    float res = p / red[0];
    size_t o = ((size_t)bh * M_ + i) * M_ + j;
    a2[o] = res;
    a2b[o] = f2b(res);
}

// ---------------- zero scratch counters ----------------
__global__ void zeroN(unsigned* p, int n) {
    int i = threadIdx.x + blockIdx.x * 64;
    if (i < n) p[i] = 0u;
}

__global__ __launch_bounds__(256) void a2_maxes(const float* __restrict__ a2, unsigned* red) {
    int bh = blockIdx.x, t = threadIdx.x;
    const float* A = a2 + (size_t)bh * M_ * M_;
    float rs = 0, cs = 0;
    for (int j = 0; j < M_; j++) rs += A[t * M_ + j];
    for (int i = 0; i < M_; i++) cs += A[i * M_ + t];
    __shared__ float lr[256], lc[256];
    lr[t] = rs; lc[t] = cs; __syncthreads();
    for (int off = 128; off > 0; off >>= 1) {
        if (t < off) { lr[t] = fmaxf(lr[t], lr[t + off]); lc[t] = fmaxf(lc[t], lc[t + off]); }
        __syncthreads();
    }
    if (t == 0) {
        atomicMax(red + 0, __float_as_uint(lr[0]));
        atomicMax(red + 1, __float_as_uint(lc[0]));
    }
}

__global__ __launch_bounds__(256) void pinv_init2(const float* __restrict__ a2,
                                                  const unsigned* __restrict__ red,
                                                  ushort_t* __restrict__ zA,
                                                  ushort_t* __restrict__ zAT) {
    __shared__ float tile[32][33];
    int bt = blockIdx.z; int j0 = blockIdx.x * 32, i0 = blockIdx.y * 32;
    float invd = 1.f / (__uint_as_float(red[0]) * __uint_as_float(red[1]));
    const float* Ab = a2 + ((size_t)bt << 16);
    size_t bo = (size_t)bt << 16;
    int t = threadIdx.x;
    #pragma unroll
    for (int u = 0; u < 4; u++) {
        int lin = t + 256 * u; int r = lin >> 5, c = lin & 31;
        float vv = Ab[(size_t)(i0 + r) * M_ + j0 + c] * invd;
        tile[r][c] = vv;
        zAT[bo + (size_t)(i0 + r) * M_ + j0 + c] = f2b(vv);
    }
    __syncthreads();
    #pragma unroll
    for (int u = 0; u < 4; u++) {
        int lin = t + 256 * u; int cc = lin >> 5, rr = lin & 31;
        zA[bo + (size_t)(j0 + cc) * M_ + i0 + rr] = f2b(tile[rr][cc]);
    }
}

// ---------------- fused 6-iteration Newton-Schulz pinv (persistent) ----------------
// grid (4,2,32): 8 blocks per bh, all co-resident (256 blocks, 28KB LDS, 4 waves).
// Per-bh barrier: monotonic counter + device-scope atomics + fences.
__global__ __launch_bounds__(256) void pinv_fused(const ushort_t* __restrict__ a2b,
                                                  ushort_t* zA, ushort_t* zAT,
                                                  ushort_t* zB, ushort_t* zBT,
                                                  ushort_t* xz, ushort_t* t1T,
                                                  ushort_t* t2T, ushort_t* t3T,
                                                  float* zf, unsigned* cnt) {
    __shared__ __align__(16) ushort_t As[128][72];
    __shared__ __align__(16) ushort_t Bs[64][72];
    int t = threadIdx.x; int bt = blockIdx.z;
    int n0 = blockIdx.x * 64, m0 = blockIdx.y * 128;
    int w = t >> 6, lane = t & 63;
    int wr = (w >> 1) * 64, wc = (w & 1) * 32;
    int l15 = lane & 15, quad = lane >> 4, kq = quad * 8;
    int rbase = t >> 3, c8 = (t & 7) * 8;
    size_t bto = (size_t)bt << 16;
    unsigned bar = 0;

    // one 128x64 gemm step: C = coefI*I + scale*(A @ BT^T), optional outputs
    auto gstep = [&](const ushort_t* A, const ushort_t* BT, ushort_t* outN,
                     ushort_t* outT, ushort_t* outT1, float* outF,
                     float coefI, float scale) {
        const ushort_t* Ab = A + bto;
        const ushort_t* Bb = BT + bto;
        fvec4 acc[4][2] = {};
        for (int kc = 0; kc < M_; kc += 64) {
            #pragma unroll
            for (int u = 0; u < 4; u++) {
                int rr = rbase + 32 * u;
                *(float4*)&As[rr][c8] = *(const float4*)(Ab + (size_t)(m0 + rr) * M_ + kc + c8);
                if (u < 2)
                    *(float4*)&Bs[rr][c8] = *(const float4*)(Bb + (size_t)(n0 + rr) * M_ + kc + c8);
            }
            __syncthreads();
            #pragma unroll
            for (int ks = 0; ks < 64; ks += 32) {
                bfrag8 a[4], b[2];
                #pragma unroll
                for (int r = 0; r < 4; r++) a[r] = *(bfrag8*)&As[wr + r * 16 + l15][ks + kq];
                #pragma unroll
                for (int c = 0; c < 2; c++) b[c] = *(bfrag8*)&Bs[wc + c * 16 + l15][ks + kq];
                #pragma unroll
                for (int r = 0; r < 4; r++)
                    #pragma unroll
                    for (int c = 0; c < 2; c++)
                        acc[r][c] = __builtin_amdgcn_mfma_f32_16x16x32_bf16(a[r], b[c], acc[r][c], 0, 0, 0);
            }
            __syncthreads();
        }
        if (outN || outF) {
            #pragma unroll
            for (int r = 0; r < 4; r++) {
                #pragma unroll
                for (int reg = 0; reg < 4; reg++) {
                    int grow = m0 + wr + r * 16 + quad * 4 + reg;
                    #pragma unroll
                    for (int c = 0; c < 2; c++) {
                        int gcol = n0 + wc + c * 16 + l15;
                        float cv = scale * acc[r][c][reg] + (grow == gcol ? coefI : 0.f);
                        if (outN) outN[bto + (size_t)grow * M_ + gcol] = f2b(cv);
                        if (outF) outF[bto + (size_t)grow * M_ + gcol] = cv;
                    }
                }
            }
        }
        if (outT || outT1) {
            ushort_t (*Ct)[65] = (ushort_t(*)[65])&As[0][0];
            #pragma unroll
            for (int r = 0; r < 4; r++) {
                #pragma unroll
                for (int reg = 0; reg < 4; reg++) {
                    int lr = wr + r * 16 + quad * 4 + reg;
                    #pragma unroll
                    for (int c = 0; c < 2; c++) {
                        int lc = wc + c * 16 + l15;
                        float cv = scale * acc[r][c][reg] + ((m0 + lr) == (n0 + lc) ? coefI : 0.f);
                        Ct[lr][lc] = f2b(cv);
                    }
                }
            }
            __syncthreads();
            int j = t & 63, half = t >> 6, i0 = half * 32;
            #pragma unroll
            for (int vq = 0; vq < 4; vq++) {
                union { uint4 u4; ushort_t s[8]; } o1, o2;
                #pragma unroll
                for (int e = 0; e < 8; e++) {
                    int il = i0 + vq * 8 + e;
                    ushort_t bv = Ct[il][j];
                    o1.s[e] = bv;
                    o2.s[e] = f2b(((m0 + il) == (n0 + j) ? 7.f : 0.f) - b2f(bv));
                }
                size_t dst = bto + (size_t)(n0 + j) * M_ + m0 + i0 + vq * 8;
                if (outT)  *(uint4*)&outT[dst]  = o1.u4;
                if (outT1) *(uint4*)&outT1[dst] = o2.u4;
            }
        }
    };

    auto bh_bar = [&]() {
        bar++;
        unsigned target = 8u * bar;
        __syncthreads();
        if (t == 0) {
            __threadfence();
            atomicAdd(cnt + bt, 1u);
            while (atomicAdd(cnt + bt, 0u) < target)
                __builtin_amdgcn_s_sleep(2);
        }
        __syncthreads();
        __threadfence();
    };

    ushort_t *za = zA, *zaT = zAT, *zb = zB, *zbT = zBT;
    for (int it = 0; it < 6; it++) {
        // xz = a2@z ; t1T = (7I - xz)^T
        gstep(a2b, zaT, xz, nullptr, t1T, nullptr, 0.f, 1.f);
        bh_bar();
        // t2T = (15I - xz@t1)^T
        gstep(xz, t1T, nullptr, t2T, nullptr, nullptr, 15.f, -1.f);
        bh_bar();
        // t3T = (13I - xz@t2)^T
        gstep(xz, t2T, nullptr, t3T, nullptr, nullptr, 13.f, -1.f);
        bh_bar();
        // z' = 0.25 z@t3 (last iter: only fp32 zf needed)
        if (it < 5) {
            gstep(za, t3T, zb, zbT, nullptr, nullptr, 0.f, 0.25f);
            bh_bar();
        } else {
            gstep(za, t3T, nullptr, nullptr, nullptr, zf, 0.f, 0.25f);
        }
        ushort_t* tp;
        tp = za; za = zb; zb = tp;
        tp = zaT; zaT = zbT; zbT = tp;
    }
}

// ---------------- MFMA flash (no-max softmax): O = softmax(Q K^T) @ V ----------------
template<int NCH, int TRANSV>
__global__ __launch_bounds__(256) void flash_mfma(const ushort_t* __restrict__ Q,
                                                  const ushort_t* __restrict__ K,
                                                  const ushort_t* __restrict__ V,
                                                  ushort_t* __restrict__ Obf,
                                                  float* __restrict__ Opart,
                                                  float* __restrict__ lout,
                                                  int nq, int nk) {
    int bh = blockIdx.y;
    int nqt = nq >> 6;
    int qt = blockIdx.x % nqt;
    int ch = blockIdx.x / nqt;
    int q0 = qt * 64;
    int chunk = nk / NCH;
    int j0 = ch * chunk, j1 = j0 + chunk;

    __shared__ __align__(16) ushort_t qs[64][72];
    __shared__ __align__(16) ushort_t ks[64][72];
    __shared__ __align__(16) ushort_t vts[64][72];
    __shared__ __align__(16) ushort_t pb[64][72];

    int t = threadIdx.x;
    int w = t >> 6, lane = t & 63;
    int l15 = lane & 15, quad = lane >> 4, kq = quad * 8;
    int wrow = w * 16;

    const ushort_t* Qb = Q + ((size_t)bh * nq + q0) * DH_;
    #pragma unroll
    for (int u = 0; u < 2; u++) {
        int lin = t + 256 * u;
        int r = lin >> 3, cc = (lin & 7) * 8;
        *(uint4*)&qs[r][cc] = *(const uint4*)(Qb + r * DH_ + cc);
    }

    fvec4 Oacc[4];
    #pragma unroll
    for (int nt = 0; nt < 4; nt++)
        #pragma unroll
        for (int reg = 0; reg < 4; reg++) Oacc[nt][reg] = 0.f;
    float l_[4] = {0.f, 0.f, 0.f, 0.f};

    const ushort_t* VTbase = V + (size_t)bh * DH_ * nk;     // TRANSV==0 layout
    for (int j = j0; j < j1; j += 64) {
        const ushort_t* Kb = K + ((size_t)bh * nk + j) * DH_;
        const ushort_t* Vb = V + ((size_t)bh * nk + j) * DH_; // TRANSV==1 layout
        #pragma unroll
        for (int u = 0; u < 2; u++) {
            int lin = t + 256 * u;
            int r = lin >> 3, cc = (lin & 7) * 8;
            *(uint4*)&ks[r][cc] = *(const uint4*)(Kb + r * DH_ + cc);
            if (TRANSV == 0) {
                *(uint4*)&vts[r][cc] = *(const uint4*)(VTbase + (size_t)r * nk + j + cc);
            } else {
                union { uint4 u4; ushort_t s[8]; } vv;
                vv.u4 = *(const uint4*)(Vb + r * DH_ + cc);
                #pragma unroll
                for (int m = 0; m < 8; m++) vts[cc + m][r] = vv.s[m];
            }
        }
        __syncthreads();

        fvec4 S[4];
        #pragma unroll
        for (int ct = 0; ct < 4; ct++)
            #pragma unroll
            for (int reg = 0; reg < 4; reg++) S[ct][reg] = 0.f;
        bfrag8 aq0 = *(bfrag8*)&qs[wrow + l15][kq];
        bfrag8 aq1 = *(bfrag8*)&qs[wrow + l15][32 + kq];
        #pragma unroll
        for (int ct = 0; ct < 4; ct++) {
            bfrag8 b0 = *(bfrag8*)&ks[ct * 16 + l15][kq];
            bfrag8 b1 = *(bfrag8*)&ks[ct * 16 + l15][32 + kq];
            S[ct] = __builtin_amdgcn_mfma_f32_16x16x32_bf16(aq0, b0, S[ct], 0, 0, 0);
            S[ct] = __builtin_amdgcn_mfma_f32_16x16x32_bf16(aq1, b1, S[ct], 0, 0, 0);
        }

        float ps[4] = {0.f, 0.f, 0.f, 0.f};
        #pragma unroll
        for (int ct = 0; ct < 4; ct++) {
            #pragma unroll
            for (int reg = 0; reg < 4; reg++) {
                float pv = __expf(S[ct][reg]);
                ps[reg] += pv;
                pb[wrow + quad * 4 + reg][ct * 16 + l15] = f2b(pv);
            }
        }
        #pragma unroll
        for (int reg = 0; reg < 4; reg++) {
            float s = ps[reg];
            s += __shfl_xor(s, 1);
            s += __shfl_xor(s, 2);
            s += __shfl_xor(s, 4);
            s += __shfl_xor(s, 8);
            l_[reg] += s;
        }

        bfrag8 ap0 = *(bfrag8*)&pb[wrow + l15][kq];
        bfrag8 ap1 = *(bfrag8*)&pb[wrow + l15][32 + kq];
        #pragma unroll
        for (int nt = 0; nt < 4; nt++) {
            bfrag8 b0 = *(bfrag8*)&vts[nt * 16 + l15][kq];
            bfrag8 b1 = *(bfrag8*)&vts[nt * 16 + l15][32 + kq];
            Oacc[nt] = __builtin_amdgcn_mfma_f32_16x16x32_bf16(ap0, b0, Oacc[nt], 0, 0, 0);
            Oacc[nt] = __builtin_amdgcn_mfma_f32_16x16x32_bf16(ap1, b1, Oacc[nt], 0, 0, 0);
        }
        __syncthreads();
    }

    if (NCH == 1) {
        #pragma unroll
        for (int reg = 0; reg < 4; reg++) {
            float inv = 1.f / l_[reg];
            #pragma unroll
            for (int nt = 0; nt < 4; nt++)
                qs[wrow + quad * 4 + reg][nt * 16 + l15] = f2b(Oacc[nt][reg] * inv);
        }
        __syncthreads();
        ushort_t* Ob = Obf + ((size_t)bh * nq + q0) * DH_;
        #pragma unroll
        for (int u = 0; u < 2; u++) {
            int lin = t + 256 * u;
            int r = lin >> 3, i = (lin & 7) * 8;
            *(uint4*)(Ob + (size_t)r * DH_ + i) = *(uint4*)&qs[r][i];
        }
    } else {
        size_t rows_per_ch = (size_t)BH_ * nq;
        #pragma unroll
        for (int reg = 0; reg < 4; reg++) {
            size_t rowg = (size_t)bh * nq + q0 + wrow + quad * 4 + reg;
            #pragma unroll
            for (int nt = 0; nt < 4; nt++)
                Opart[((size_t)ch * rows_per_ch + rowg) * DH_ + nt * 16 + l15] = Oacc[nt][reg];
            if (l15 == 0)
                lout[(size_t)ch * rows_per_ch + rowg] = l_[reg];
        }
    }
}

// combine 4 key-chunks -> a3v fp32 (no-max: plain sums)
__global__ __launch_bounds__(256) void flash_combine(const float* __restrict__ apart,
                                                     const float* __restrict__ lpart,
                                                     float* __restrict__ a3v) {
    int idx = blockIdx.x * 256 + threadIdx.x;
    int d = idx & 63; int row = idx >> 6;
    const int R = BH_ * M_;
    float l = lpart[row] + lpart[row + R] + lpart[row + 2 * R] + lpart[row + 3 * R];
    size_t e = (size_t)row * DH_ + d;
    const size_t CH = (size_t)R * DH_;
    float o = apart[e] + apart[e + CH] + apart[e + 2 * CH] + apart[e + 3 * CH];
    a3v[e] = o / l;
}

// ---------------- W^T = (z @ a3v)^T : bf16 out [bh][64][256] ----------------
__global__ __launch_bounds__(256) void zmm_kernel(const float* __restrict__ Z,
                                                  const float* __restrict__ A3V,
                                                  ushort_t* __restrict__ WmT) {
    int bh = blockIdx.y;
    int i0 = blockIdx.x * 64;
    __shared__ float zs[64][65];
    __shared__ float as[64][65];
    int t = threadIdx.x;
    int d = t & 63, r4 = t >> 6;
    float acc[16] = {};
    for (int kt_ = 0; kt_ < 4; kt_++) {
        #pragma unroll
        for (int u = 0; u < 4; u++) {
            int lin = t + 256 * u;
            int r = lin >> 4, c4 = lin & 15;
            float4 zv = *(const float4*)(Z + ((size_t)bh * M_ + i0 + r) * M_ + kt_ * 64 + c4 * 4);
            zs[r][c4 * 4 + 0] = zv.x; zs[r][c4 * 4 + 1] = zv.y;
            zs[r][c4 * 4 + 2] = zv.z; zs[r][c4 * 4 + 3] = zv.w;
            float4 av = *(const float4*)(A3V + ((size_t)bh * M_ + kt_ * 64 + r) * DH_ + c4 * 4);
            as[r][c4 * 4 + 0] = av.x; as[r][c4 * 4 + 1] = av.y;
            as[r][c4 * 4 + 2] = av.z; as[r][c4 * 4 + 3] = av.w;
        }
        __syncthreads();
        #pragma unroll
        for (int kk = 0; kk < 64; kk++) {
            float av = as[kk][d];
            #pragma unroll
            for (int rr = 0; rr < 16; rr++) acc[rr] += zs[r4 + rr * 4][kk] * av;
        }
        __syncthreads();
    }
    #pragma unroll
    for (int rr = 0; rr < 16; rr++)
        WmT[((size_t)bh * DH_ + d) * M_ + i0 + r4 + rr * 4] = f2b(acc[rr]);
}

// ---------------- conv residual: outh_bf = bf16(ctx_bf + conv(v)) ----------------
__global__ __launch_bounds__(256) void conv_kernel(const ushort_t* __restrict__ V,
                                                   const float* __restrict__ cw,
                                                   const ushort_t* __restrict__ ctxb,
                                                   ushort_t* __restrict__ outb) {
    int bh = blockIdx.y;
    int h = bh & 7;
    int i0 = blockIdx.x * 64;
    __shared__ float vb[96][64];
    __shared__ float wloc[33];
    int t = threadIdx.x;
    if (t < 33) wloc[t] = cw[h * 33 + t];
    #pragma unroll
    for (int u = 0; u < 3; u++) {
        int lin = t + 256 * u;
        int r = lin >> 3, cc = (lin & 7) * 8;
        int gi = i0 - 16 + r;
        union { uint4 u4; ushort_t s[8]; } val;
        if (gi >= 0 && gi < N_)
            val.u4 = *(const uint4*)(V + ((size_t)bh * N_ + gi) * DH_ + cc);
        else
            val.u4 = make_uint4(0, 0, 0, 0);
        #pragma unroll
        for (int m = 0; m < 8; m++) vb[r][cc + m] = b2f(val.s[m]);
    }
    __syncthreads();
    int d = t & 63, rb = t >> 6;
    for (int u = 0; u < 16; u++) {
        int r = rb * 16 + u;
        float s = 0.f;
        #pragma unroll
        for (int kk = 0; kk < 33; kk++) s += wloc[kk] * vb[r + kk][d];
        size_t o = ((size_t)bh * N_ + i0 + r) * DH_ + d;
        outb[o] = f2b(b2f(ctxb[o]) + s);
    }
}

extern "C" void kernel_launch(void* const* d_in, const int* in_sizes, int n_in,
                              void* d_out, int out_size, void* d_ws, size_t ws_size,
                              hipStream_t stream) {
    const float* x      = (const float*)d_in[0];
    const float* ln_w   = (const float*)d_in[1];
    const float* ln_b   = (const float*)d_in[2];
    const float* w_qkv  = (const float*)d_in[3];
    const float* w_out  = (const float*)d_in[4];
    const float* b_out  = (const float*)d_in[5];
    const float* conv_w = (const float*)d_in[6];
    const float* omega  = (const float*)d_in[7];
    float* out = (float*)d_out;

    // ---- workspace carve ----
    float* fp = (float*)d_ws;
    float* a2    = fp;              fp += SZ_MM;
    float* a3v   = fp;              fp += SZ_LM;
    float* zf    = fp;              fp += SZ_MM;
    float* apart = fp;              fp += SZ_QKVH / 4;
    float* lpart = fp;              fp += 4 * BH_ * M_;
    ushort_t* us = (ushort_t*)fp;
    ushort_t* wqkvT = us;           us += DIM_ * 3 * DIM_;
    ushort_t* woT   = us;           us += DIM_ * DIM_;
    ushort_t* a2b   = us;           us += SZ_MM;
    ushort_t* zA    = us;           us += SZ_MM;
    ushort_t* zAT   = us;           us += SZ_MM;
    ushort_t* zB    = us;           us += SZ_MM;
    ushort_t* zBT   = us;           us += SZ_MM;
    ushort_t* qb    = us;           us += SZ_QKVH;
    ushort_t* kb    = us;           us += SZ_QKVH;
    ushort_t* vb    = us;           us += SZ_QKVH;
    ushort_t* ctxb  = us;           us += SZ_QKVH;       // pinv bf16 temps overlay (disjoint)
    ushort_t* outhb = us;           us += SZ_QKVH;       // aliased as nxb (disjoint lifetime)
    ushort_t* ql    = us;           us += SZ_LM;
    ushort_t* kl    = us;           us += SZ_LM;
    ushort_t* WmT   = us;           us += SZ_LM;
    unsigned* red   = (unsigned*)us;                      // red[0..1] maxes, red[2..33] barriers
    unsigned* cnt   = red + 2;
    ushort_t* nxb = outhb;
    // pinv bf16 temporaries overlay ctxb (ctxb written only after pinv finishes)
    ushort_t* xz  = ctxb;
    ushort_t* t1T = xz  + SZ_MM;
    ushort_t* t2T = t1T + SZ_MM;
    ushort_t* t3T = t2T + SZ_MM;

    ln_kernel<<<B_ * N_, 256, 0, stream>>>(x, ln_w, ln_b, nxb);
    tcast<<<dim3(48, 16), 256, 0, stream>>>(w_qkv, wqkvT, DIM_, 3 * DIM_);
    tcast<<<dim3(16, 16), 256, 0, stream>>>(w_out, woT, DIM_, DIM_);
    gemm_bt128<0><<<dim3(12, 128), 256, 0, stream>>>(nxb, wqkvT, qb, kb, vb,
                                                     nullptr, nullptr, nullptr, nullptr);
    landmark_kernel<<<dim3(256, 2), 256, 0, stream>>>(qb, kb, ql, kl);
    sim2_softmax<<<dim3(M_, BH_), 256, 0, stream>>>(ql, kl, a2, a2b);
    zeroN<<<1, 64, 0, stream>>>(red, 34);
    a2_maxes<<<BH_, 256, 0, stream>>>(a2, red);
    pinv_init2<<<dim3(8, 8, 32), 256, 0, stream>>>(a2, red, zA, zAT);

    // fused Newton-Schulz: 24 GEMM steps, 1 dispatch, per-bh barriers
    pinv_fused<<<dim3(4, 2, BH_), 256, 0, stream>>>(a2b, zA, zAT, zB, zBT,
                                                    xz, t1T, t2T, t3T, zf, cnt);

    // a3v = softmax(q_l k^T) @ v  (4 key-chunks + combine; V transposed in LDS)
    flash_mfma<4, 1><<<dim3(16, BH_), 256, 0, stream>>>(ql, kb, vb, nullptr, apart, lpart, M_, N_);
    flash_combine<<<(BH_ * M_ * DH_) / 256, 256, 0, stream>>>(apart, lpart, a3v);
    // WmT = (z @ a3v)^T
    zmm_kernel<<<dim3(4, BH_), 256, 0, stream>>>(zf, a3v, WmT);
    // ctxb = bf16( softmax(q kl^T) @ Wm )
    flash_mfma<1, 0><<<dim3(64, BH_), 256, 0, stream>>>(qb, kl, WmT, ctxb, nullptr, nullptr, N_, M_);
    // outh = bf16(ctx + conv(v))
    conv_kernel<<<dim3(N_ / 64, BH_), 256, 0, stream>>>(vb, conv_w, ctxb, outhb);
    // out = omega*x + b_out + outh @ w_out
    gemm_bt128<1><<<dim3(4, 128), 256, 0, stream>>>(outhb, woT, nullptr, nullptr, nullptr,
                                                    x, b_out, omega, out);
}

// Round 8
// 1286.036 us; speedup vs baseline: 1.2689x; 1.2689x over previous
//
#include <hip/hip_runtime.h>
#include <math.h>

#define B_    4
#define N_    4096
#define DIM_  512
#define H_    8
#define DH_   64
#define M_    256
#define LGRP  16
#define BH_   (B_*H_)
#define SCALE_ 0.125f
#define LN_EPS_ 1e-5f

#define SZ_QKVH (B_*H_*N_*DH_)   /* 8388608 */
#define SZ_LM   (BH_*M_*DH_)     /* 524288  */
#define SZ_MM   (BH_*M_*M_)      /* 2097152 */

typedef unsigned short ushort_t;
typedef __attribute__((ext_vector_type(8))) short bfrag8;
typedef __attribute__((ext_vector_type(4))) float fvec4;

__device__ __forceinline__ ushort_t f2b(float f) {
    unsigned u = __float_as_uint(f);
    unsigned r = (u + 0x7fffu + ((u >> 16) & 1u)) >> 16;
    return (ushort_t)r;
}
__device__ __forceinline__ float b2f(ushort_t s) {
    return __uint_as_float(((unsigned)s) << 16);
}

// ---------------- LayerNorm -> bf16 nx ----------------
__global__ __launch_bounds__(256) void ln_kernel(const float* __restrict__ x,
                                                 const float* __restrict__ w,
                                                 const float* __restrict__ bb,
                                                 ushort_t* __restrict__ nxb) {
    int row = blockIdx.x;
    int t = threadIdx.x;
    const float* xr = x + (size_t)row * DIM_;
    float v0 = xr[t], v1 = xr[t + 256];
    float s = v0 + v1, sq = v0 * v0 + v1 * v1;
    __shared__ float ls[4], lq[4];
    for (int off = 32; off > 0; off >>= 1) {
        s  += __shfl_down(s, off);
        sq += __shfl_down(sq, off);
    }
    int wid = t >> 6, lid = t & 63;
    if (lid == 0) { ls[wid] = s; lq[wid] = sq; }
    __syncthreads();
    if (t == 0) {
        float S = 0, Q = 0;
        for (int i = 0; i < 4; i++) { S += ls[i]; Q += lq[i]; }
        ls[0] = S; lq[0] = Q;
    }
    __syncthreads();
    float mean = ls[0] * (1.f / DIM_);
    float var  = lq[0] * (1.f / DIM_) - mean * mean;
    float rs = rsqrtf(var + LN_EPS_);
    ushort_t* o = nxb + (size_t)row * DIM_;
    o[t]       = f2b((v0 - mean) * rs * w[t]       + bb[t]);
    o[t + 256] = f2b((v1 - mean) * rs * w[t + 256] + bb[t + 256]);
}

// ---------------- transpose + cast fp32 [R][C] -> bf16 [C][R] ----------------
__global__ __launch_bounds__(256) void tcast(const float* __restrict__ in,
                                             ushort_t* __restrict__ outT,
                                             int R, int C) {
    __shared__ float tile[32][33];
    int c0 = blockIdx.x * 32, r0 = blockIdx.y * 32;
    int t = threadIdx.x;
    #pragma unroll
    for (int u = 0; u < 4; u++) {
        int lin = t + 256 * u;
        int r = lin >> 5, c = lin & 31;
        tile[r][c] = in[(size_t)(r0 + r) * C + c0 + c];
    }
    __syncthreads();
    #pragma unroll
    for (int u = 0; u < 4; u++) {
        int lin = t + 256 * u;
        int cc = lin >> 5, rr = lin & 31;
        outT[(size_t)(c0 + cc) * R + r0 + rr] = f2b(tile[rr][cc]);
    }
}

// ---------------- big MFMA GEMM: C[M][N] = A[M][512] @ BT[N][512]^T ----------------
// EPI 0: qkv epilogue (bf16 q/k/v, LDS-coalesced). EPI 1: out = omega*x + bo + C.
template<int EPI>
__global__ __launch_bounds__(256) void gemm_bt128(const ushort_t* __restrict__ A,
                                                  const ushort_t* __restrict__ BT,
                                                  ushort_t* __restrict__ qb,
                                                  ushort_t* __restrict__ kb,
                                                  ushort_t* __restrict__ vb,
                                                  const float* __restrict__ x,
                                                  const float* __restrict__ bo,
                                                  const float* __restrict__ omega,
                                                  float* __restrict__ out) {
    const int K = 512;
    __shared__ __align__(16) ushort_t smem[2 * 128 * 72];
    ushort_t (*As)[72] = (ushort_t(*)[72])smem;
    ushort_t (*Bs)[72] = (ushort_t(*)[72])(smem + 128 * 72);
    int t = threadIdx.x;
    int n0 = blockIdx.x * 128, m0 = blockIdx.y * 128;
    int w = t >> 6, lane = t & 63;
    int wr = (w >> 1) * 64, wc = (w & 1) * 64;
    int l15 = lane & 15, quad = lane >> 4, kq = quad * 8;
    fvec4 acc[4][4] = {};
    int rbase = t >> 3, c8 = (t & 7) * 8;

    for (int kc = 0; kc < K; kc += 64) {
        #pragma unroll
        for (int u = 0; u < 4; u++) {
            int rr = rbase + 32 * u;
            const ushort_t* ga;
            if (EPI == 0) {
                ga = A + (size_t)(m0 + rr) * K + kc + c8;
            } else {
                int grow = m0 + rr; int b_ = grow >> 12, nn = grow & 4095;
                int col = kc + c8; int hd = col >> 6, dd = col & 63;
                ga = A + (((size_t)(b_ * H_ + hd) * N_ + nn) << 6) + dd;
            }
            *(float4*)&As[rr][c8] = *(const float4*)ga;
            *(float4*)&Bs[rr][c8] = *(const float4*)(BT + (size_t)(n0 + rr) * K + kc + c8);
        }
        __syncthreads();
        #pragma unroll
        for (int ks = 0; ks < 64; ks += 32) {
            bfrag8 a[4], b[4];
            #pragma unroll
            for (int r = 0; r < 4; r++) a[r] = *(bfrag8*)&As[wr + r * 16 + l15][ks + kq];
            #pragma unroll
            for (int c = 0; c < 4; c++) b[c] = *(bfrag8*)&Bs[wc + c * 16 + l15][ks + kq];
            #pragma unroll
            for (int r = 0; r < 4; r++)
                #pragma unroll
                for (int c = 0; c < 4; c++)
                    acc[r][c] = __builtin_amdgcn_mfma_f32_16x16x32_bf16(a[r], b[c], acc[r][c], 0, 0, 0);
        }
        __syncthreads();
    }

    if (EPI == 0) {
        int sec = n0 >> 9;                     // 0=q 1=k 2=v (tile never crosses)
        float mul = (sec == 0) ? SCALE_ : 1.0f;
        ushort_t (*Ct)[132] = (ushort_t(*)[132])smem;   // 128*132*2 = 33792 <= 36864
        #pragma unroll
        for (int r = 0; r < 4; r++) {
            #pragma unroll
            for (int reg = 0; reg < 4; reg++) {
                int lr = wr + r * 16 + quad * 4 + reg;
                #pragma unroll
                for (int c = 0; c < 4; c++) {
                    int lc = wc + c * 16 + l15;
                    Ct[lr][lc] = f2b(acc[r][c][reg] * mul);
                }
            }
        }
        __syncthreads();
        int row = t & 127, half = t >> 7;
        int grow = m0 + row; int b_ = grow >> 12, nn = grow & 4095;
        int head = ((n0 & 511) >> 6) + half;
        ushort_t* dstbuf = (sec == 0) ? qb : ((sec == 1) ? kb : vb);
        ushort_t* dp = dstbuf + (((size_t)(b_ * H_ + head) * N_ + nn) << 6);
        #pragma unroll
        for (int i = 0; i < 8; i++)
            *(uint4*)(dp + i * 8) = *(uint4*)&Ct[row][half * 64 + i * 8];
    } else {
        float om = omega[0];
        #pragma unroll
        for (int r = 0; r < 4; r++) {
            #pragma unroll
            for (int reg = 0; reg < 4; reg++) {
                int grow = m0 + wr + r * 16 + quad * 4 + reg;
                #pragma unroll
                for (int c = 0; c < 4; c++) {
                    int gcol = n0 + wc + c * 16 + l15;
                    size_t o = (size_t)grow * DIM_ + gcol;
                    out[o] = om * x[o] + bo[gcol] + acc[r][c][reg];
                }
            }
        }
    }
}

// ---------------- landmark means (bf16 in/out, uint4 vectorized) ----------------
__global__ __launch_bounds__(256) void landmark_kernel(const ushort_t* __restrict__ q,
                                                       const ushort_t* __restrict__ k,
                                                       ushort_t* __restrict__ ql,
                                                       ushort_t* __restrict__ kl) {
    int idx = blockIdx.x * 256 + threadIdx.x;    // over SZ_LM/8 = 65536
    const ushort_t* src = blockIdx.y ? k : q;
    ushort_t* dst = blockIdx.y ? kl : ql;
    int d8 = (idx & 7) * 8;
    int m = (idx >> 3) & 255;
    int bh = idx >> 11;
    const ushort_t* p = src + (((size_t)bh * N_) + m * LGRP) * DH_ + d8;
    float s[8] = {};
    #pragma unroll
    for (int j = 0; j < LGRP; j++) {
        union { uint4 u4; ushort_t sv[8]; } val;
        val.u4 = *(const uint4*)(p + (size_t)j * DH_);
        #pragma unroll
        for (int e = 0; e < 8; e++) s[e] += b2f(val.sv[e]);
    }
    union { uint4 u4; ushort_t sv[8]; } o;
    #pragma unroll
    for (int e = 0; e < 8; e++) o.sv[e] = f2b(s[e] * (1.f / LGRP));
    *(uint4*)(dst + ((size_t)bh * M_ + m) * DH_ + d8) = o.u4;
}

// ---------------- sim2 + softmax -> a2 (fp32 + bf16) ----------------
__global__ __launch_bounds__(256) void sim2_softmax(const ushort_t* __restrict__ ql,
                                                    const ushort_t* __restrict__ kl,
                                                    float* __restrict__ a2,
                                                    ushort_t* __restrict__ a2b) {
    int i = blockIdx.x, bh = blockIdx.y, j = threadIdx.x;
    __shared__ float qrow[64];
    __shared__ float red[256];
    if (j < 64) qrow[j] = b2f(ql[((size_t)bh * M_ + i) * DH_ + j]);
    __syncthreads();
    const ushort_t* kr = kl + ((size_t)bh * M_ + j) * DH_;
    float s = 0;
    #pragma unroll
    for (int d = 0; d < 64; d++) s += qrow[d] * b2f(kr[d]);
    red[j] = s; __syncthreads();
    for (int off = 128; off > 0; off >>= 1) {
        if (j < off) red[j] = fmaxf(red[j], red[j + off]);
        __syncthreads();
    }
    float mx = red[0]; __syncthreads();
    float p = __expf(s - mx);
    red[j] = p; __syncthreads();
    for (int off = 128; off > 0; off >>= 1) {
        if (j < off) red[j] += red[j + off];
        __syncthreads();
    }
    float res = p / red[0];
    size_t o = ((size_t)bh * M_ + i) * M_ + j;
    a2[o] = res;
    a2b[o] = f2b(res);
}

// ---------------- zero scratch ----------------
__global__ void zeroN(unsigned* p, int n) {
    int i = threadIdx.x + blockIdx.x * 64;
    if (i < n) p[i] = 0u;
}

// a2 rows are softmax outputs -> row sums == 1 exactly (max(col)=1).
// Only the column-sum max (ref "row") needs computing.
__global__ __launch_bounds__(256) void a2_colmax(const float* __restrict__ a2, unsigned* red) {
    int bh = blockIdx.x, t = threadIdx.x;
    const float* A = a2 + (size_t)bh * M_ * M_;
    float cs = 0;
    for (int i = 0; i < M_; i++) cs += A[i * M_ + t];
    __shared__ float lc[256];
    lc[t] = cs; __syncthreads();
    for (int off = 128; off > 0; off >>= 1) {
        if (t < off) lc[t] = fmaxf(lc[t], lc[t + off]);
        __syncthreads();
    }
    if (t == 0) {
        atomicMax(red + 1, __float_as_uint(lc[0]));
        if (bh == 0) atomicMax(red + 0, __float_as_uint(1.0f));
    }
}

__global__ __launch_bounds__(256) void pinv_init2(const float* __restrict__ a2,
                                                  const unsigned* __restrict__ red,
                                                  ushort_t* __restrict__ zA,
                                                  ushort_t* __restrict__ zAT) {
    __shared__ float tile[32][33];
    int bt = blockIdx.z; int j0 = blockIdx.x * 32, i0 = blockIdx.y * 32;
    float invd = 1.f / (__uint_as_float(red[0]) * __uint_as_float(red[1]));
    const float* Ab = a2 + ((size_t)bt << 16);
    size_t bo = (size_t)bt << 16;
    int t = threadIdx.x;
    #pragma unroll
    for (int u = 0; u < 4; u++) {
        int lin = t + 256 * u; int r = lin >> 5, c = lin & 31;
        float vv = Ab[(size_t)(i0 + r) * M_ + j0 + c] * invd;
        tile[r][c] = vv;
        zAT[bo + (size_t)(i0 + r) * M_ + j0 + c] = f2b(vv);
    }
    __syncthreads();
    #pragma unroll
    for (int u = 0; u < 4; u++) {
        int lin = t + 256 * u; int cc = lin >> 5, rr = lin & 31;
        zA[bo + (size_t)(j0 + cc) * M_ + i0 + rr] = f2b(tile[rr][cc]);
    }
}

// ---------------- one-block-per-bh fused Newton-Schulz pinv ----------------
// 32 blocks x 512 threads (8 waves). Each block owns one bh: all 24 GEMM steps
// run in-block with __syncthreads only (no inter-block sync -> no deadlock).
// Per GEMM: 2 row-passes; per pass stage A-half[128x64] + BT-full[256x64];
// each wave computes one 64x64 tile (acc = 16 fvec4). Transposed epilogues go
// through a per-wave LDS scratch (St, overlaid on Bs; [n][m] layout -> 16B
// vectorized stores). __threadfence before pass-end barrier invalidates L1 so
// same-CU global RAW across steps is safe.
__global__ __launch_bounds__(512) void pinv_block(const ushort_t* __restrict__ a2b,
                                                  ushort_t* zA, ushort_t* zAT,
                                                  ushort_t* zB, ushort_t* zBT,
                                                  ushort_t* xz, ushort_t* t1T,
                                                  ushort_t* t2T, ushort_t* t3T,
                                                  float* zf) {
    __shared__ __align__(16) ushort_t As[128][72];
    __shared__ __align__(16) ushort_t Bs[256][72];
    int t = threadIdx.x;
    int bt = blockIdx.x;
    size_t bto = (size_t)bt << 16;
    int w = t >> 6, lane = t & 63;
    int l15 = lane & 15, quad = lane >> 4, kq = quad * 8;
    int lm = w >> 2, ln = w & 3;
    int rA = t >> 3, c8 = (t & 7) * 8;
    ushort_t (*St)[64][36] = (ushort_t (*)[64][36])&Bs[0][0];   // 8*64*36*2 = 36864 == sizeof(Bs)

    auto gstep = [&](const ushort_t* AG, const ushort_t* BTG,
                     ushort_t* oN, float* oF, ushort_t* oT, bool t1form,
                     float coefI, float scale) {
        const ushort_t* Ab = AG + bto;
        const ushort_t* Bb = BTG + bto;
        for (int p = 0; p < 2; p++) {
            int gm0 = p * 128 + lm * 64;
            int gn0 = ln * 64;
            fvec4 acc[4][4] = {};
            for (int kc = 0; kc < M_; kc += 64) {
                #pragma unroll
                for (int u = 0; u < 2; u++)
                    *(float4*)&As[rA + 64 * u][c8] =
                        *(const float4*)(Ab + (size_t)(p * 128 + rA + 64 * u) * M_ + kc + c8);
                #pragma unroll
                for (int u = 0; u < 4; u++)
                    *(float4*)&Bs[rA + 64 * u][c8] =
                        *(const float4*)(Bb + (size_t)(rA + 64 * u) * M_ + kc + c8);
                __syncthreads();
                #pragma unroll
                for (int ks = 0; ks < 64; ks += 32) {
                    bfrag8 a[4], b[4];
                    #pragma unroll
                    for (int r = 0; r < 4; r++) a[r] = *(bfrag8*)&As[lm * 64 + r * 16 + l15][ks + kq];
                    #pragma unroll
                    for (int c = 0; c < 4; c++) b[c] = *(bfrag8*)&Bs[ln * 64 + c * 16 + l15][ks + kq];
                    #pragma unroll
                    for (int r = 0; r < 4; r++)
                        #pragma unroll
                        for (int c = 0; c < 4; c++)
                            acc[r][c] = __builtin_amdgcn_mfma_f32_16x16x32_bf16(a[r], b[c], acc[r][c], 0, 0, 0);
                }
                __syncthreads();
            }
            // ---- epilogue (wave-private 64x64 tile) ----
            if (oN || oF) {
                #pragma unroll
                for (int r = 0; r < 4; r++) {
                    #pragma unroll
                    for (int reg = 0; reg < 4; reg++) {
                        int grow = gm0 + r * 16 + quad * 4 + reg;
                        #pragma unroll
                        for (int c = 0; c < 4; c++) {
                            int gcol = gn0 + c * 16 + l15;
                            float cv = scale * acc[r][c][reg] + (grow == gcol ? coefI : 0.f);
                            if (oN) oN[bto + (size_t)grow * M_ + gcol] = f2b(cv);
                            if (oF) oF[bto + (size_t)grow * M_ + gcol] = cv;
                        }
                    }
                }
            }
            if (oT) {
                #pragma unroll
                for (int h = 0; h < 2; h++) {
                    #pragma unroll
                    for (int r2 = 0; r2 < 2; r2++) {
                        int r = h * 2 + r2;
                        #pragma unroll
                        for (int reg = 0; reg < 4; reg++) {
                            int grow = gm0 + r * 16 + quad * 4 + reg;
                            int i = r2 * 16 + quad * 4 + reg;
                            #pragma unroll
                            for (int c = 0; c < 4; c++) {
                                int gcol = gn0 + c * 16 + l15;
                                float cv = scale * acc[r][c][reg] + (grow == gcol ? coefI : 0.f);
                                St[w][c * 16 + l15][i] = f2b(cv);
                            }
                        }
                    }
                    // in-wave LDS RAW: compiler inserts lgkm waits
                    int n = gn0 + lane;
                    #pragma unroll
                    for (int i8 = 0; i8 < 4; i8++) {
                        union { uint4 u4; ushort_t s[8]; } o;
                        o.u4 = *(uint4*)&St[w][lane][i8 * 8];
                        if (t1form) {
                            #pragma unroll
                            for (int e = 0; e < 8; e++) {
                                int m = gm0 + h * 32 + i8 * 8 + e;
                                o.s[e] = f2b((m == n ? 7.f : 0.f) - b2f(o.s[e]));
                            }
                        }
                        *(uint4*)&oT[bto + (size_t)n * M_ + gm0 + h * 32 + i8 * 8] = o.u4;
                    }
                }
            }
            __threadfence();     // drain stores + invalidate L1 (global RAW across steps)
            __syncthreads();     // St/Bs reuse + step ordering
        }
    };

    ushort_t *za = zA, *zaT = zAT, *zb = zB, *zbT = zBT;
    for (int it = 0; it < 6; it++) {
        // xz = a2@z ; t1T = (7I - xz)^T
        gstep(a2b, zaT, xz, nullptr, t1T, true, 0.f, 1.f);
        // t2T = (15I - xz@t1)^T
        gstep(xz, t1T, nullptr, nullptr, t2T, false, 15.f, -1.f);
        // t3T = (13I - xz@t2)^T
        gstep(xz, t2T, nullptr, nullptr, t3T, false, 13.f, -1.f);
        // z' = 0.25 z@t3
        if (it < 5) gstep(za, t3T, zb, nullptr, zbT, false, 0.f, 0.25f);
        else        gstep(za, t3T, nullptr, zf, nullptr, false, 0.f, 0.25f);
        ushort_t* tp;
        tp = za; za = zb; zb = tp;
        tp = zaT; zaT = zbT; zbT = tp;
    }
}

// ---------------- MFMA flash (no-max softmax): O = softmax(Q K^T) @ V ----------------
template<int NCH, int TRANSV>
__global__ __launch_bounds__(256) void flash_mfma(const ushort_t* __restrict__ Q,
                                                  const ushort_t* __restrict__ K,
                                                  const ushort_t* __restrict__ V,
                                                  ushort_t* __restrict__ Obf,
                                                  float* __restrict__ Opart,
                                                  float* __restrict__ lout,
                                                  int nq, int nk) {
    int bh = blockIdx.y;
    int nqt = nq >> 6;
    int qt = blockIdx.x % nqt;
    int ch = blockIdx.x / nqt;
    int q0 = qt * 64;
    int chunk = nk / NCH;
    int j0 = ch * chunk, j1 = j0 + chunk;

    __shared__ __align__(16) ushort_t qs[64][72];
    __shared__ __align__(16) ushort_t ks[64][72];
    __shared__ __align__(16) ushort_t vts[64][72];
    __shared__ __align__(16) ushort_t pb[64][72];

    int t = threadIdx.x;
    int w = t >> 6, lane = t & 63;
    int l15 = lane & 15, quad = lane >> 4, kq = quad * 8;
    int wrow = w * 16;

    const ushort_t* Qb = Q + ((size_t)bh * nq + q0) * DH_;
    #pragma unroll
    for (int u = 0; u < 2; u++) {
        int lin = t + 256 * u;
        int r = lin >> 3, cc = (lin & 7) * 8;
        *(uint4*)&qs[r][cc] = *(const uint4*)(Qb + r * DH_ + cc);
    }

    fvec4 Oacc[4];
    #pragma unroll
    for (int nt = 0; nt < 4; nt++)
        #pragma unroll
        for (int reg = 0; reg < 4; reg++) Oacc[nt][reg] = 0.f;
    float l_[4] = {0.f, 0.f, 0.f, 0.f};

    const ushort_t* VTbase = V + (size_t)bh * DH_ * nk;     // TRANSV==0 layout
    for (int j = j0; j < j1; j += 64) {
        const ushort_t* Kb = K + ((size_t)bh * nk + j) * DH_;
        const ushort_t* Vb = V + ((size_t)bh * nk + j) * DH_; // TRANSV==1 layout
        #pragma unroll
        for (int u = 0; u < 2; u++) {
            int lin = t + 256 * u;
            int r = lin >> 3, cc = (lin & 7) * 8;
            *(uint4*)&ks[r][cc] = *(const uint4*)(Kb + r * DH_ + cc);
            if (TRANSV == 0) {
                *(uint4*)&vts[r][cc] = *(const uint4*)(VTbase + (size_t)r * nk + j + cc);
            } else {
                union { uint4 u4; ushort_t s[8]; } vv;
                vv.u4 = *(const uint4*)(Vb + r * DH_ + cc);
                #pragma unroll
                for (int m = 0; m < 8; m++) vts[cc + m][r] = vv.s[m];
            }
        }
        __syncthreads();

        fvec4 S[4];
        #pragma unroll
        for (int ct = 0; ct < 4; ct++)
            #pragma unroll
            for (int reg = 0; reg < 4; reg++) S[ct][reg] = 0.f;
        bfrag8 aq0 = *(bfrag8*)&qs[wrow + l15][kq];
        bfrag8 aq1 = *(bfrag8*)&qs[wrow + l15][32 + kq];
        #pragma unroll
        for (int ct = 0; ct < 4; ct++) {
            bfrag8 b0 = *(bfrag8*)&ks[ct * 16 + l15][kq];
            bfrag8 b1 = *(bfrag8*)&ks[ct * 16 + l15][32 + kq];
            S[ct] = __builtin_amdgcn_mfma_f32_16x16x32_bf16(aq0, b0, S[ct], 0, 0, 0);
            S[ct] = __builtin_amdgcn_mfma_f32_16x16x32_bf16(aq1, b1, S[ct], 0, 0, 0);
        }

        float ps[4] = {0.f, 0.f, 0.f, 0.f};
        #pragma unroll
        for (int ct = 0; ct < 4; ct++) {
            #pragma unroll
            for (int reg = 0; reg < 4; reg++) {
                float pv = __expf(S[ct][reg]);
                ps[reg] += pv;
                pb[wrow + quad * 4 + reg][ct * 16 + l15] = f2b(pv);
            }
        }
        #pragma unroll
        for (int reg = 0; reg < 4; reg++) {
            float s = ps[reg];
            s += __shfl_xor(s, 1);
            s += __shfl_xor(s, 2);
            s += __shfl_xor(s, 4);
            s += __shfl_xor(s, 8);
            l_[reg] += s;
        }

        bfrag8 ap0 = *(bfrag8*)&pb[wrow + l15][kq];
        bfrag8 ap1 = *(bfrag8*)&pb[wrow + l15][32 + kq];
        #pragma unroll
        for (int nt = 0; nt < 4; nt++) {
            bfrag8 b0 = *(bfrag8*)&vts[nt * 16 + l15][kq];
            bfrag8 b1 = *(bfrag8*)&vts[nt * 16 + l15][32 + kq];
            Oacc[nt] = __builtin_amdgcn_mfma_f32_16x16x32_bf16(ap0, b0, Oacc[nt], 0, 0, 0);
            Oacc[nt] = __builtin_amdgcn_mfma_f32_16x16x32_bf16(ap1, b1, Oacc[nt], 0, 0, 0);
        }
        __syncthreads();
    }

    if (NCH == 1) {
        #pragma unroll
        for (int reg = 0; reg < 4; reg++) {
            float inv = 1.f / l_[reg];
            #pragma unroll
            for (int nt = 0; nt < 4; nt++)
                qs[wrow + quad * 4 + reg][nt * 16 + l15] = f2b(Oacc[nt][reg] * inv);
        }
        __syncthreads();
        ushort_t* Ob = Obf + ((size_t)bh * nq + q0) * DH_;
        #pragma unroll
        for (int u = 0; u < 2; u++) {
            int lin = t + 256 * u;
            int r = lin >> 3, i = (lin & 7) * 8;
            *(uint4*)(Ob + (size_t)r * DH_ + i) = *(uint4*)&qs[r][i];
        }
    } else {
        size_t rows_per_ch = (size_t)BH_ * nq;
        #pragma unroll
        for (int reg = 0; reg < 4; reg++) {
            size_t rowg = (size_t)bh * nq + q0 + wrow + quad * 4 + reg;
            #pragma unroll
            for (int nt = 0; nt < 4; nt++)
                Opart[((size_t)ch * rows_per_ch + rowg) * DH_ + nt * 16 + l15] = Oacc[nt][reg];
            if (l15 == 0)
                lout[(size_t)ch * rows_per_ch + rowg] = l_[reg];
        }
    }
}

// combine 4 key-chunks -> a3v fp32 (no-max: plain sums)
__global__ __launch_bounds__(256) void flash_combine(const float* __restrict__ apart,
                                                     const float* __restrict__ lpart,
                                                     float* __restrict__ a3v) {
    int idx = blockIdx.x * 256 + threadIdx.x;
    int d = idx & 63; int row = idx >> 6;
    const int R = BH_ * M_;
    float l = lpart[row] + lpart[row + R] + lpart[row + 2 * R] + lpart[row + 3 * R];
    size_t e = (size_t)row * DH_ + d;
    const size_t CH = (size_t)R * DH_;
    float o = apart[e] + apart[e + CH] + apart[e + 2 * CH] + apart[e + 3 * CH];
    a3v[e] = o / l;
}

// ---------------- W^T = (z @ a3v)^T : bf16 out [bh][64][256] ----------------
__global__ __launch_bounds__(256) void zmm_kernel(const float* __restrict__ Z,
                                                  const float* __restrict__ A3V,
                                                  ushort_t* __restrict__ WmT) {
    int bh = blockIdx.y;
    int i0 = blockIdx.x * 64;
    __shared__ float zs[64][65];
    __shared__ float as[64][65];
    int t = threadIdx.x;
    int d = t & 63, r4 = t >> 6;
    float acc[16] = {};
    for (int kt_ = 0; kt_ < 4; kt_++) {
        #pragma unroll
        for (int u = 0; u < 4; u++) {
            int lin = t + 256 * u;
            int r = lin >> 4, c4 = lin & 15;
            float4 zv = *(const float4*)(Z + ((size_t)bh * M_ + i0 + r) * M_ + kt_ * 64 + c4 * 4);
            zs[r][c4 * 4 + 0] = zv.x; zs[r][c4 * 4 + 1] = zv.y;
            zs[r][c4 * 4 + 2] = zv.z; zs[r][c4 * 4 + 3] = zv.w;
            float4 av = *(const float4*)(A3V + ((size_t)bh * M_ + kt_ * 64 + r) * DH_ + c4 * 4);
            as[r][c4 * 4 + 0] = av.x; as[r][c4 * 4 + 1] = av.y;
            as[r][c4 * 4 + 2] = av.z; as[r][c4 * 4 + 3] = av.w;
        }
        __syncthreads();
        #pragma unroll
        for (int kk = 0; kk < 64; kk++) {
            float av = as[kk][d];
            #pragma unroll
            for (int rr = 0; rr < 16; rr++) acc[rr] += zs[r4 + rr * 4][kk] * av;
        }
        __syncthreads();
    }
    #pragma unroll
    for (int rr = 0; rr < 16; rr++)
        WmT[((size_t)bh * DH_ + d) * M_ + i0 + r4 + rr * 4] = f2b(acc[rr]);
}

// ---------------- conv residual: outh_bf = bf16(ctx_bf + conv(v)) ----------------
__global__ __launch_bounds__(256) void conv_kernel(const ushort_t* __restrict__ V,
                                                   const float* __restrict__ cw,
                                                   const ushort_t* __restrict__ ctxb,
                                                   ushort_t* __restrict__ outb) {
    int bh = blockIdx.y;
    int h = bh & 7;
    int i0 = blockIdx.x * 64;
    __shared__ float vb[96][64];
    __shared__ float wloc[33];
    int t = threadIdx.x;
    if (t < 33) wloc[t] = cw[h * 33 + t];
    #pragma unroll
    for (int u = 0; u < 3; u++) {
        int lin = t + 256 * u;
        int r = lin >> 3, cc = (lin & 7) * 8;
        int gi = i0 - 16 + r;
        union { uint4 u4; ushort_t s[8]; } val;
        if (gi >= 0 && gi < N_)
            val.u4 = *(const uint4*)(V + ((size_t)bh * N_ + gi) * DH_ + cc);
        else
            val.u4 = make_uint4(0, 0, 0, 0);
        #pragma unroll
        for (int m = 0; m < 8; m++) vb[r][cc + m] = b2f(val.s[m]);
    }
    __syncthreads();
    int d = t & 63, rb = t >> 6;
    for (int u = 0; u < 16; u++) {
        int r = rb * 16 + u;
        float s = 0.f;
        #pragma unroll
        for (int kk = 0; kk < 33; kk++) s += wloc[kk] * vb[r + kk][d];
        size_t o = ((size_t)bh * N_ + i0 + r) * DH_ + d;
        outb[o] = f2b(b2f(ctxb[o]) + s);
    }
}

extern "C" void kernel_launch(void* const* d_in, const int* in_sizes, int n_in,
                              void* d_out, int out_size, void* d_ws, size_t ws_size,
                              hipStream_t stream) {
    const float* x      = (const float*)d_in[0];
    const float* ln_w   = (const float*)d_in[1];
    const float* ln_b   = (const float*)d_in[2];
    const float* w_qkv  = (const float*)d_in[3];
    const float* w_out  = (const float*)d_in[4];
    const float* b_out  = (const float*)d_in[5];
    const float* conv_w = (const float*)d_in[6];
    const float* omega  = (const float*)d_in[7];
    float* out = (float*)d_out;

    // ---- workspace carve ----
    float* fp = (float*)d_ws;
    float* a2    = fp;              fp += SZ_MM;
    float* a3v   = fp;              fp += SZ_LM;
    float* zf    = fp;              fp += SZ_MM;
    float* apart = fp;              fp += SZ_QKVH / 4;
    float* lpart = fp;              fp += 4 * BH_ * M_;
    ushort_t* us = (ushort_t*)fp;
    ushort_t* wqkvT = us;           us += DIM_ * 3 * DIM_;
    ushort_t* woT   = us;           us += DIM_ * DIM_;
    ushort_t* a2b   = us;           us += SZ_MM;
    ushort_t* zA    = us;           us += SZ_MM;
    ushort_t* zAT   = us;           us += SZ_MM;
    ushort_t* zB    = us;           us += SZ_MM;
    ushort_t* zBT   = us;           us += SZ_MM;
    ushort_t* qb    = us;           us += SZ_QKVH;
    ushort_t* kb    = us;           us += SZ_QKVH;
    ushort_t* vb    = us;           us += SZ_QKVH;
    ushort_t* ctxb  = us;           us += SZ_QKVH;       // pinv bf16 temps overlay (disjoint)
    ushort_t* outhb = us;           us += SZ_QKVH;       // aliased as nxb (disjoint lifetime)
    ushort_t* ql    = us;           us += SZ_LM;
    ushort_t* kl    = us;           us += SZ_LM;
    ushort_t* WmT   = us;           us += SZ_LM;
    unsigned* red   = (unsigned*)us;
    ushort_t* nxb = outhb;
    // pinv bf16 temporaries overlay ctxb (ctxb written only after pinv finishes)
    ushort_t* xz  = ctxb;
    ushort_t* t1T = xz  + SZ_MM;
    ushort_t* t2T = t1T + SZ_MM;
    ushort_t* t3T = t2T + SZ_MM;

    ln_kernel<<<B_ * N_, 256, 0, stream>>>(x, ln_w, ln_b, nxb);
    tcast<<<dim3(48, 16), 256, 0, stream>>>(w_qkv, wqkvT, DIM_, 3 * DIM_);
    tcast<<<dim3(16, 16), 256, 0, stream>>>(w_out, woT, DIM_, DIM_);
    gemm_bt128<0><<<dim3(12, 128), 256, 0, stream>>>(nxb, wqkvT, qb, kb, vb,
                                                     nullptr, nullptr, nullptr, nullptr);
    landmark_kernel<<<dim3(256, 2), 256, 0, stream>>>(qb, kb, ql, kl);
    sim2_softmax<<<dim3(M_, BH_), 256, 0, stream>>>(ql, kl, a2, a2b);
    zeroN<<<1, 64, 0, stream>>>(red, 2);
    a2_colmax<<<BH_, 256, 0, stream>>>(a2, red);
    pinv_init2<<<dim3(8, 8, 32), 256, 0, stream>>>(a2, red, zA, zAT);

    // fused Newton-Schulz: one block per bh, intra-block sync only
    pinv_block<<<BH_, 512, 0, stream>>>(a2b, zA, zAT, zB, zBT, xz, t1T, t2T, t3T, zf);

    // a3v = softmax(q_l k^T) @ v  (4 key-chunks + combine; V transposed in LDS)
    flash_mfma<4, 1><<<dim3(16, BH_), 256, 0, stream>>>(ql, kb, vb, nullptr, apart, lpart, M_, N_);
    flash_combine<<<(BH_ * M_ * DH_) / 256, 256, 0, stream>>>(apart, lpart, a3v);
    // WmT = (z @ a3v)^T
    zmm_kernel<<<dim3(4, BH_), 256, 0, stream>>>(zf, a3v, WmT);
    // ctxb = bf16( softmax(q kl^T) @ Wm )
    flash_mfma<1, 0><<<dim3(64, BH_), 256, 0, stream>>>(qb, kl, WmT, ctxb, nullptr, nullptr, N_, M_);
    // outh = bf16(ctx + conv(v))
    conv_kernel<<<dim3(N_ / 64, BH_), 256, 0, stream>>>(vb, conv_w, ctxb, outhb);
    // out = omega*x + b_out + outh @ w_out
    gemm_bt128<1><<<dim3(4, 128), 256, 0, stream>>>(outhb, woT, nullptr, nullptr, nullptr,
                                                    x, b_out, omega, out);
}